// Round 7
// baseline (79.103 us; speedup 1.0000x reference)
//
#include <hip/hip_runtime.h>
#include <hip/hip_bf16.h>

#define N_ROWS 8192
#define K_CENT 128
#define D_DIM  512
#define LDS_PITCH 520   // 512 + 8 pad ushorts; row stride 1040B (16B-aligned)

typedef short v8s __attribute__((ext_vector_type(8)));
typedef unsigned short v8u __attribute__((ext_vector_type(8)));
typedef float v4f __attribute__((ext_vector_type(4)));

// fp32 -> bf16 round-to-nearest-even (bit trick; inputs are finite normals)
__device__ inline unsigned short f2bf(float f) {
    union { float f; unsigned u; } v; v.f = f;
    unsigned r = v.u + 0x7FFFu + ((v.u >> 16) & 1u);
    return (unsigned short)(r >> 16);
}

// Single fused kernel. Block = 8 waves = 512 threads, one 16-row x-tile.
// Stage x -> LDS (bf16) once; wave g handles centroid group g with DIRECT
// fp32 c-loads (256 KiB total, L2-resident), in-register conversion.
// All three quadratic terms come from the matrix pipe:
//   acc  = X.C^T   (the dot products)
//   accx = X.X^T   -> diagonal = ||x_m||^2   (diag[m] at lane 20*(m>>2)+(m&3)... 
//                     precisely: lane = 16*(m>>2)+m, reg = m&3)
//   accc = C.C^T   -> diagonal = ||c_n||^2   (same mapping in n)
// D layout (gfx950 16x16x32, verified m89/m91): col = lane&15, row = quad*4+reg.
// Grid 512 blocks = 2/CU x 8 waves = 16 waves/CU; launch_bounds(512,4) caps
// VGPR at 128 so all stay resident. x read from HBM exactly once; no ws.
__global__ __launch_bounds__(512, 4) void dist_fused(const float* __restrict__ x,
                                                     const float* __restrict__ c,
                                                     float* __restrict__ out) {
    __shared__ unsigned short xlds[16 * LDS_PITCH];

    const int t    = threadIdx.x;
    const int lane = t & 63;
    const int g    = t >> 6;             // wave index == centroid group 0..7
    const int rowbase = blockIdx.x * 16;

    // ---- Stage x tile -> LDS: thread t converts floats {j*4096 + 8t .. +7} ----
    const float* xs = x + (size_t)rowbase * D_DIM;
    #pragma unroll
    for (int j = 0; j < 2; ++j) {
        int base = j * 4096 + t * 8;             // flat float index in 16x512 tile
        float4 v0 = *(const float4*)(xs + base);
        float4 v1 = *(const float4*)(xs + base + 4);
        int row = base >> 9;
        int k   = base & 511;
        v8u p;
        p[0] = f2bf(v0.x); p[1] = f2bf(v0.y); p[2] = f2bf(v0.z); p[3] = f2bf(v0.w);
        p[4] = f2bf(v1.x); p[5] = f2bf(v1.y); p[6] = f2bf(v1.z); p[7] = f2bf(v1.w);
        *(v8u*)&xlds[row * LDS_PITCH + k] = p;   // single ds_write_b128
    }
    __syncthreads();

    // ---- MFMA loop: LDS afrag + direct fp32 c-load converted to bfrag ----
    const int n16  = lane & 15;
    const int quad = lane >> 4;
    const float* cptr = c + (size_t)(g * 16 + n16) * D_DIM + quad * 8;
    const unsigned short* aptr = &xlds[n16 * LDS_PITCH + quad * 8];

    v4f acc  = (v4f){0.f, 0.f, 0.f, 0.f};
    v4f accx = (v4f){0.f, 0.f, 0.f, 0.f};
    v4f accc = (v4f){0.f, 0.f, 0.f, 0.f};
    #pragma unroll
    for (int i = 0; i < 16; ++i) {
        float4 q0 = *(const float4*)(cptr + i * 32);
        float4 q1 = *(const float4*)(cptr + i * 32 + 4);
        v8s af = *(const v8s*)(aptr + i * 32);
        v8s bf;
        bf[0] = (short)f2bf(q0.x); bf[1] = (short)f2bf(q0.y);
        bf[2] = (short)f2bf(q0.z); bf[3] = (short)f2bf(q0.w);
        bf[4] = (short)f2bf(q1.x); bf[5] = (short)f2bf(q1.y);
        bf[6] = (short)f2bf(q1.z); bf[7] = (short)f2bf(q1.w);
        acc  = __builtin_amdgcn_mfma_f32_16x16x32_bf16(af, bf, acc,  0, 0, 0);
        accx = __builtin_amdgcn_mfma_f32_16x16x32_bf16(af, af, accx, 0, 0, 0);
        accc = __builtin_amdgcn_mfma_f32_16x16x32_bf16(bf, bf, accc, 0, 0, 0);
    }

    // ---- Epilogue: both norms from matrix-pipe diagonals ----
    // ||c_{g*16+n16}||^2 = C.C^T diag[n16]: reg n16&3, lane 16*(n16>>2)+n16
    const int csrc = 16 * (n16 >> 2) + n16;
    float cd0 = __shfl(accc[0], csrc, 64);
    float cd1 = __shfl(accc[1], csrc, 64);
    float cd2 = __shfl(accc[2], csrc, 64);
    float cd3 = __shfl(accc[3], csrc, 64);
    const int cr = n16 & 3;
    float cn = cr == 0 ? cd0 : cr == 1 ? cd1 : cr == 2 ? cd2 : cd3;

    #pragma unroll
    for (int r = 0; r < 4; ++r) {
        float xn = __shfl(accx[r], 20 * quad + r, 64);   // X.X^T diag[quad*4+r]
        int row = rowbase + quad * 4 + r;
        float d2 = xn + cn - 2.0f * acc[r];
        d2 = d2 > 0.f ? d2 : 0.f;
        out[(size_t)row * K_CENT + g * 16 + n16] = sqrtf(d2);
    }
}

extern "C" void kernel_launch(void* const* d_in, const int* in_sizes, int n_in,
                              void* d_out, int out_size, void* d_ws, size_t ws_size,
                              hipStream_t stream) {
    const float* x = (const float*)d_in[0];
    const float* c = (const float*)d_in[1];
    float* out = (float*)d_out;
    (void)d_ws; (void)ws_size;

    dist_fused<<<N_ROWS / 16, 512, 0, stream>>>(x, c, out);
}

// Round 8
// 73.551 us; speedup vs baseline: 1.0755x; 1.0755x over previous
//
#include <hip/hip_runtime.h>
#include <hip/hip_bf16.h>

#define N_ROWS 8192
#define K_CENT 128
#define D_DIM  512
#define LDS_PITCH 520   // 512 + 8 pad ushorts; row stride 1040B (16B-aligned)

typedef short v8s __attribute__((ext_vector_type(8)));
typedef unsigned short v8u __attribute__((ext_vector_type(8)));
typedef float v4f __attribute__((ext_vector_type(4)));

// fp32 -> bf16 round-to-nearest-even (bit trick; inputs are finite normals)
__device__ inline unsigned short f2bf(float f) {
    union { float f; unsigned u; } v; v.f = f;
    unsigned r = v.u + 0x7FFFu + ((v.u >> 16) & 1u);
    return (unsigned short)(r >> 16);
}

// One wave per centroid row: exact fp32 ||c||^2 + bf16 copy. 128 waves total.
__global__ __launch_bounds__(256) void prep_centroids(const float* __restrict__ c,
                                                      float* __restrict__ cnorm,
                                                      unsigned short* __restrict__ cb) {
    int wave = (int)((blockIdx.x * blockDim.x + threadIdx.x) >> 6);
    int lane = threadIdx.x & 63;
    if (wave >= K_CENT) return;
    const float* src = c + (size_t)wave * D_DIM;
    float4 a = ((const float4*)src)[lane];
    float4 b = ((const float4*)src)[64 + lane];
    float s = a.x*a.x + a.y*a.y + a.z*a.z + a.w*a.w
            + b.x*b.x + b.y*b.y + b.z*b.z + b.w*b.w;
    #pragma unroll
    for (int off = 32; off >= 1; off >>= 1) s += __shfl_xor(s, off, 64);
    if (lane == 0) cnorm[wave] = s;
    unsigned short* dst = cb + (size_t)wave * D_DIM;
    ushort4 p0, p1;
    p0.x = f2bf(a.x); p0.y = f2bf(a.y); p0.z = f2bf(a.z); p0.w = f2bf(a.w);
    p1.x = f2bf(b.x); p1.y = f2bf(b.y); p1.z = f2bf(b.z); p1.w = f2bf(b.w);
    ((ushort4*)dst)[lane]      = p0;
    ((ushort4*)dst)[64 + lane] = p1;
}

// Block = 16 waves = 1024 threads, one 32-row x-tile staged to LDS (bf16) once.
// Wave w: centroid group g = w&7, row-half h = w>>3. Each wave: ds_read_b128
// afrag + global v8s bfrag + MFMA. ||x||^2 via matrix pipe (accx = mfma(af,af),
// X.X^T diag[quad*4+r] at lane 20*quad+r; D layout col=lane&15, row=quad*4+reg,
// verified m89/m91). cnorm exact fp32 from prep.
// Grid 256 blocks = 1/CU x 16 waves = 16 waves/CU; launch_bounds(1024,4) caps
// VGPR at 128 so all stay resident. vs R6: 2x rows/block halves per-row cb
// L2 traffic (64 -> 32 MiB total); x still fetched from HBM exactly once.
__global__ __launch_bounds__(1024, 4) void dist_kernel(const float* __restrict__ x,
                                                       const unsigned short* __restrict__ cb,
                                                       const float* __restrict__ cnorm,
                                                       float* __restrict__ out) {
    __shared__ unsigned short xlds[32 * LDS_PITCH];

    const int t    = threadIdx.x;
    const int lane = t & 63;
    const int wave = t >> 6;             // 0..15
    const int g    = wave & 7;           // centroid group
    const int h    = wave >> 3;          // row half 0/1
    const int tilebase = blockIdx.x * 32;

    // ---- Stage 32x512 x tile -> LDS: thread t converts floats {j*8192 + 8t .. +7} ----
    const float* xs = x + (size_t)tilebase * D_DIM;
    #pragma unroll
    for (int j = 0; j < 2; ++j) {
        int base = j * 8192 + t * 8;             // flat float index in 32x512 tile
        float4 v0 = *(const float4*)(xs + base);
        float4 v1 = *(const float4*)(xs + base + 4);
        int row = base >> 9;
        int k   = base & 511;
        v8u p;
        p[0] = f2bf(v0.x); p[1] = f2bf(v0.y); p[2] = f2bf(v0.z); p[3] = f2bf(v0.w);
        p[4] = f2bf(v1.x); p[5] = f2bf(v1.y); p[6] = f2bf(v1.z); p[7] = f2bf(v1.w);
        *(v8u*)&xlds[row * LDS_PITCH + k] = p;   // single ds_write_b128
    }
    __syncthreads();

    // ---- MFMA loop ----
    const int n16  = lane & 15;
    const int quad = lane >> 4;
    const int rowbase = tilebase + h * 16;
    const unsigned short* bptr = cb + (size_t)(g * 16 + n16) * D_DIM + quad * 8;
    const unsigned short* aptr = &xlds[(h * 16 + n16) * LDS_PITCH + quad * 8];

    v4f acc  = (v4f){0.f, 0.f, 0.f, 0.f};
    v4f accx = (v4f){0.f, 0.f, 0.f, 0.f};
    #pragma unroll
    for (int i = 0; i < 16; ++i) {
        v8s af = *(const v8s*)(aptr + i * 32);
        v8s bf = *(const v8s*)(bptr + i * 32);
        acc  = __builtin_amdgcn_mfma_f32_16x16x32_bf16(af, bf, acc, 0, 0, 0);
        accx = __builtin_amdgcn_mfma_f32_16x16x32_bf16(af, af, accx, 0, 0, 0);
    }

    // ---- Epilogue: xnorm from X.X^T diagonal, cnorm exact fp32 ----
    const float cn = cnorm[g * 16 + n16];
    #pragma unroll
    for (int r = 0; r < 4; ++r) {
        float xn = __shfl(accx[r], 20 * quad + r, 64);   // diag[quad*4+r]
        int row = rowbase + quad * 4 + r;
        float d2 = xn + cn - 2.0f * acc[r];
        d2 = d2 > 0.f ? d2 : 0.f;
        out[(size_t)row * K_CENT + g * 16 + n16] = sqrtf(d2);
    }
}

// Correctness fallback if ws is unexpectedly tiny: one thread per output.
__global__ void naive_kernel(const float* __restrict__ x, const float* __restrict__ c,
                             float* __restrict__ out) {
    int idx = blockIdx.x * blockDim.x + threadIdx.x;
    if (idx >= N_ROWS * K_CENT) return;
    int n = idx / K_CENT, k = idx % K_CENT;
    const float* xr = x + (size_t)n * D_DIM;
    const float* cr = c + (size_t)k * D_DIM;
    float s = 0.f;
    for (int d = 0; d < D_DIM; ++d) { float df = xr[d] - cr[d]; s += df * df; }
    out[idx] = sqrtf(s);
}

extern "C" void kernel_launch(void* const* d_in, const int* in_sizes, int n_in,
                              void* d_out, int out_size, void* d_ws, size_t ws_size,
                              hipStream_t stream) {
    const float* x = (const float*)d_in[0];
    const float* c = (const float*)d_in[1];
    float* out = (float*)d_out;

    // ws layout: cnorm (512 B) | cb (128 KiB)
    const size_t need = 512 + (size_t)K_CENT * D_DIM * sizeof(unsigned short);
    if (ws_size < need) {
        int total = N_ROWS * K_CENT;
        naive_kernel<<<(total + 255) / 256, 256, 0, stream>>>(x, c, out);
        return;
    }

    float* cnorm = (float*)d_ws;
    unsigned short* cb = (unsigned short*)((char*)d_ws + 512);

    prep_centroids<<<(K_CENT * 64 + 255) / 256, 256, 0, stream>>>(c, cnorm, cb);
    dist_kernel<<<N_ROWS / 32, 1024, 0, stream>>>(x, cb, cnorm, out);
}